// Round 5
// baseline (176.485 us; speedup 1.0000x reference)
//
#include <hip/hip_runtime.h>

#define VOCAB 1024
#define HIDDEN 64
#define N_POS 131072            // 32*64*64 positions
#define Q_ELEMS 8388608
#define BPOS 256                // positions per block
#define NBLK 512                // N_POS / BPOS

// d_out layout (floats): [0]=loss, [1..8388608]=quantized_st (NCHW),
// [8388609]=perplexity, [8388610..]=one_hot [131072,1024]
#define OUT_Q_OFF 1
#define OUT_PPL_OFF 8388609
#define OUT_OH_OFF 8388610ULL

typedef __attribute__((ext_vector_type(8))) short short8v;  // bf16x8 MFMA frag
typedef __attribute__((ext_vector_type(4))) float f32x4;

__device__ __forceinline__ short bf16r(float f) {
    union { float f; unsigned u; } v; v.f = f;
    unsigned r = v.u + 0x7FFFu + ((v.u >> 16) & 1u);   // RNE
    return (short)(r >> 16);
}

// 384 threads: tid 0-255 = 4 compute waves, tid 256-383 = 2 writer waves.
// Writer waves free-run the block's 1 MB of one_hot zeros on their own
// per-wave vmcnt queue; compute waves' queues only ever hold loads, so no
// barrier forces a store drain on the compute side. Whole bf16 codebook
// staged once in 128 KB LDS -> only 3 block barriers.
__global__ __launch_bounds__(384, 1) void vq_main(
    const float* __restrict__ in, const float* __restrict__ cb,
    float* __restrict__ out, float* __restrict__ ws_loss,
    unsigned* __restrict__ counts)
{
    __shared__ short cbs[VOCAB * HIDDEN];   // 128 KB, XOR-swizzled bf16
    __shared__ float bsqs[VOCAB];           // -0.5*|c|^2
    __shared__ unsigned hist[VOCAB];
    __shared__ int   idx_lds[BPOS];
    __shared__ float lred[4];

    const int tid  = threadIdx.x;
    const int base = blockIdx.x * BPOS;
    const int b    = base >> 12;            // NCHW batch index, uniform
    const int hw0  = base & 4095;
    float* ohflat = out + OUT_OH_OFF + (size_t)base * VOCAB;   // 262144 floats
    float4* oh4   = (float4*)(ohflat + 2);                     // 16B aligned

    if (tid < 256) {
        // ======================= compute waves =======================
        const int wid = tid >> 6, lane = tid & 63;
        const int l15 = lane & 15, kg = lane >> 4;
        const int kg4 = kg << 2, kgb = kg << 4;

        for (int k = tid; k < VOCAB; k += 256) hist[k] = 0u;

        // ---- x fragments + per-lane |x|^2 partials ----
        // B-frag: col = l15 (position), k = kh*32 + kg*8 + e
        short8v xf[4][2];
        float xsq[4];
#pragma unroll
        for (int bt = 0; bt < 4; ++bt) {
            xsq[bt] = 0.f;
#pragma unroll
            for (int kh = 0; kh < 2; ++kh) {
                const float* xp = in + (size_t)b * 262144
                                + (size_t)(kh * 32 + kg * 8) * 4096
                                + hw0 + wid * 64 + bt * 16 + l15;
                short8v v;
#pragma unroll
                for (int e = 0; e < 8; ++e) {
                    float x = xp[(size_t)e * 4096];
                    xsq[bt] = fmaf(x, x, xsq[bt]);
                    v[e] = bf16r(x);
                }
                xf[bt][kh] = v;
            }
        }

        // ---- stage ALL 1024 codes as swizzled bf16; bsqs via 16-lane shfl ----
        {
            const float4* src = (const float4*)cb;
#pragma unroll 4
            for (int it = 0; it < 64; ++it) {
                int i = tid + it * 256;
                int row = i >> 4, c4 = i & 15;
                float4 v = src[i];
                float ss = v.x * v.x + v.y * v.y + v.z * v.z + v.w * v.w;
                ss += __shfl_xor(ss, 1);
                ss += __shfl_xor(ss, 2);
                ss += __shfl_xor(ss, 4);
                ss += __shfl_xor(ss, 8);
                unsigned lo = ((unsigned)(unsigned short)bf16r(v.x))
                            | ((unsigned)(unsigned short)bf16r(v.y) << 16);
                unsigned hi = ((unsigned)(unsigned short)bf16r(v.z))
                            | ((unsigned)(unsigned short)bf16r(v.w) << 16);
                int boff = row * 128 + ((c4 * 8) ^ ((row & 7) << 4));
                *(uint2*)((char*)cbs + boff) = make_uint2(lo, hi);
                if (c4 == 0) bsqs[row] = -0.5f * ss;
            }
        }
        asm volatile("s_waitcnt vmcnt(0) lgkmcnt(0)" ::: "memory");
        __builtin_amdgcn_sched_barrier(0);
        __builtin_amdgcn_s_barrier();                      // B1: staging done
        __builtin_amdgcn_sched_barrier(0);

        // ---- MFMA argmax over all 1024 codes ----
        float rm[4];
#pragma unroll
        for (int bt = 0; bt < 4; ++bt) rm[bt] = -3.4e38f;

        for (int ct = 0; ct < 64; ++ct) {
            const int rbase = ct * 16 + l15;               // A-frag row = code
            const char* arow = (const char*)cbs + rbase * 128;
            const int sw = (rbase & 7) << 4;
            short8v a0 = *(const short8v*)(arow + (kgb ^ sw));          // k 0..31
            short8v a1 = *(const short8v*)(arow + ((64 + kgb) ^ sw));   // k 32..63
            f32x4 bsq4 = *(const f32x4*)&bsqs[ct * 16 + kg4];
            const unsigned jb = (unsigned)(ct * 16 + kg4);
#pragma unroll
            for (int bt = 0; bt < 4; ++bt) {
                f32x4 acc = bsq4;
                acc = __builtin_amdgcn_mfma_f32_16x16x32_bf16(a0, xf[bt][0], acc, 0, 0, 0);
                acc = __builtin_amdgcn_mfma_f32_16x16x32_bf16(a1, xf[bt][1], acc, 0, 0, 0);
#pragma unroll
                for (int r = 0; r < 4; ++r) {
                    unsigned pj = (__float_as_uint(acc[r]) & 0xFFFFFC00u) | (jb + r);
                    rm[bt] = fmaxf(rm[bt], __uint_as_float(pj));
                }
            }
        }

        // ---- cross-lane reduce: max(m) and sum(|x|^2) over kg lanes ----
        float lsum = 0.f;
#pragma unroll
        for (int bt = 0; bt < 4; ++bt) {
            float m  = rm[bt];
            float xs = xsq[bt];
            m  = fmaxf(m, __shfl_xor(m, 16));
            xs += __shfl_xor(xs, 16);
            m  = fmaxf(m, __shfl_xor(m, 32));
            xs += __shfl_xor(xs, 32);
            if (kg == 0) {
                unsigned mu = __float_as_uint(m);
                int j = (int)(mu & 1023u);
                float mval = __uint_as_float(mu & 0xFFFFFC00u);
                idx_lds[wid * 64 + bt * 16 + l15] = j;
                atomicAdd(&hist[j], 1u);
                lsum += xs - 2.f * mval;     // |x-c|^2 = |x|^2 - 2(x.c - 0.5|c|^2)
            }
        }
        asm volatile("s_waitcnt lgkmcnt(0)" ::: "memory");
        __builtin_amdgcn_sched_barrier(0);
        __builtin_amdgcn_s_barrier();                      // B2: zeros drained
        __builtin_amdgcn_sched_barrier(0);

        // ---- q write (fp32 gather), the 1.0 scatter, hist flush, loss ----
        const int jf = idx_lds[tid];
        const float* cr = cb + (size_t)jf * HIDDEN;
        float* qp = out + OUT_Q_OFF + (size_t)b * 262144 + hw0 + tid;
#pragma unroll
        for (int c = 0; c < HIDDEN; ++c)
            qp[(size_t)c * 4096] = cr[c];        // quantized_st == q exactly
        ohflat[(size_t)tid * VOCAB + jf] = 1.0f;
        for (int k = tid; k < VOCAB; k += 256) {
            unsigned h = hist[k];
            if (h) atomicAdd(&counts[k], h);
        }
#pragma unroll
        for (int off = 32; off; off >>= 1) lsum += __shfl_down(lsum, off);
        if (lane == 0) lred[wid] = lsum;
        asm volatile("s_waitcnt lgkmcnt(0)" ::: "memory");
        __builtin_amdgcn_sched_barrier(0);
        __builtin_amdgcn_s_barrier();                      // B3: lred visible
        __builtin_amdgcn_sched_barrier(0);
        if (tid == 0) atomicAdd(ws_loss, lred[0] + lred[1] + lred[2] + lred[3]);
    } else {
        // ======================= writer waves =======================
        const int w = tid - 256;                 // 0..127
        const float4 z4 = make_float4(0.f, 0.f, 0.f, 0.f);
        if (w == 0)   *(float2*)ohflat = make_float2(0.f, 0.f);              // head
        if (w == 127) *(float2*)(ohflat + 262142) = make_float2(0.f, 0.f);   // tail
        // pre-B1 batch: stays under the 63-deep per-wave vmcnt cap, so we
        // reach B1 immediately while these drain under compute's staging.
#pragma unroll 4
        for (int k = 0; k < 60; ++k) oh4[w + k * 128] = z4;
        __builtin_amdgcn_sched_barrier(0);
        __builtin_amdgcn_s_barrier();                      // B1
        __builtin_amdgcn_sched_barrier(0);
        // free-running zero stream (self-paced by vmcnt cap at drain rate)
        for (int k = 60; k < 512; ++k) {
            int i = w + k * 128;
            if (i < 65535) oh4[i] = z4;
        }
        asm volatile("s_waitcnt vmcnt(0)" ::: "memory");   // all zeros visible
        __builtin_amdgcn_sched_barrier(0);
        __builtin_amdgcn_s_barrier();                      // B2
        __builtin_amdgcn_sched_barrier(0);
        __builtin_amdgcn_s_barrier();                      // B3
        __builtin_amdgcn_sched_barrier(0);
    }
}

__global__ void vq_finalize(const unsigned* __restrict__ counts,
                            const float* __restrict__ ws_loss,
                            float* __restrict__ out)
{
    __shared__ double red[4];
    const int tid = threadIdx.x;
    double s = 0.0;
    for (int k = tid; k < VOCAB; k += 256) {
        double p = (double)counts[k] / (double)N_POS;
        s += -p * log(p + 1e-10);
    }
#pragma unroll
    for (int off = 32; off; off >>= 1) s += __shfl_down(s, off);
    if ((tid & 63) == 0) red[tid >> 6] = s;
    __syncthreads();
    if (tid == 0) {
        double e = red[0] + red[1] + red[2] + red[3];
        out[OUT_PPL_OFF] = (float)exp(e);
        out[0] = ws_loss[0] * 1.25f / (float)Q_ELEMS;
    }
}

extern "C" void kernel_launch(void* const* d_in, const int* in_sizes, int n_in,
                              void* d_out, int out_size, void* d_ws, size_t ws_size,
                              hipStream_t stream) {
    const float* in = (const float*)d_in[0];
    const float* cb = (const float*)d_in[1];
    float* out = (float*)d_out;

    float*    ws_loss = (float*)d_ws;                 // 4 B
    unsigned* counts  = (unsigned*)d_ws + 64;         // bytes 256..4352

    hipMemsetAsync(d_ws, 0, 4352, stream);            // zero loss accum + counts
    vq_main<<<NBLK, 384, 0, stream>>>(in, cb, out, ws_loss, counts);
    vq_finalize<<<1, 256, 0, stream>>>(counts, ws_loss, out);
}

// Round 6
// 167.215 us; speedup vs baseline: 1.0554x; 1.0554x over previous
//
#include <hip/hip_runtime.h>

#define VOCAB 1024
#define HIDDEN 64
#define N_POS 131072            // 32*64*64 positions
#define Q_ELEMS 8388608
#define BPOS 512                // positions per block
#define NBLK 256                // N_POS / BPOS  (1 block per CU)

// d_out layout (floats): [0]=loss, [1..8388608]=quantized_st (NCHW),
// [8388609]=perplexity, [8388610..]=one_hot [131072,1024]
#define OUT_Q_OFF 1
#define OUT_PPL_OFF 8388609
#define OUT_OH_OFF 8388610ULL

typedef __attribute__((ext_vector_type(8))) short short8v;  // bf16x8 MFMA frag
typedef __attribute__((ext_vector_type(4))) float f32x4;

__device__ __forceinline__ short bf16r(float f) {
    union { float f; unsigned u; } v; v.f = f;
    unsigned r = v.u + 0x7FFFu + ((v.u >> 16) & 1u);   // RNE
    return (short)(r >> 16);
}

// 384 threads: tid 0-255 = 4 compute waves, tid 256-383 = 2 writer waves.
// Pipeline: compute produces idx for tile t -> barrier -> writers stream that
// tile's one_hot rows with the 1.0 FOLDED INTO the zero stream (no scatter,
// no store-drain handoff), while compute runs tile t+1 / q-writes / loss.
__global__ __launch_bounds__(384, 1) void vq_main(
    const float* __restrict__ in, const float* __restrict__ cb,
    float* __restrict__ out, float* __restrict__ ws_loss,
    unsigned* __restrict__ counts)
{
    __shared__ short cbs[VOCAB * HIDDEN];   // 128 KB, XOR-swizzled bf16
    __shared__ float bsqs[VOCAB];           // -0.5*|c|^2
    __shared__ unsigned hist[VOCAB];
    __shared__ int   idx_lds[BPOS];         // absolute row within block

    const int tid  = threadIdx.x;
    const int base = blockIdx.x * BPOS;
    const int b    = base >> 12;            // NCHW batch index, uniform
    const int hw0  = base & 4095;
    float* ohflat = out + OUT_OH_OFF + (size_t)base * VOCAB;   // 524288 floats
    float4* oh4   = (float4*)(ohflat + 2);                     // 16B aligned

    for (int k = tid; k < VOCAB; k += 384) hist[k] = 0u;

    // ---- stage ALL 1024 codes as swizzled bf16 (all 6 waves help) ----
    {
        const float4* src = (const float4*)cb;
        for (int i = tid; i < VOCAB * 16; i += 384) {
            int row = i >> 4, c4 = i & 15;
            float4 v = src[i];
            float ss = v.x * v.x + v.y * v.y + v.z * v.z + v.w * v.w;
            ss += __shfl_xor(ss, 1);
            ss += __shfl_xor(ss, 2);
            ss += __shfl_xor(ss, 4);
            ss += __shfl_xor(ss, 8);
            unsigned lo = ((unsigned)(unsigned short)bf16r(v.x))
                        | ((unsigned)(unsigned short)bf16r(v.y) << 16);
            unsigned hi = ((unsigned)(unsigned short)bf16r(v.z))
                        | ((unsigned)(unsigned short)bf16r(v.w) << 16);
            int boff = row * 128 + ((c4 * 8) ^ ((row & 7) << 4));
            *(uint2*)((char*)cbs + boff) = make_uint2(lo, hi);
            if (c4 == 0) bsqs[row] = -0.5f * ss;
        }
    }

    if (tid < 256) {
        // ======================= compute waves =======================
        const int wid = tid >> 6, lane = tid & 63;
        const int l15 = lane & 15, kg = lane >> 4;
        const int kg4 = kg << 2, kgb = kg << 4;

        // ---- x fragments + |x|^2 for BOTH tiles (overlaps staging) ----
        short8v xf[2][4][2];
        float xsq[2][4];
#pragma unroll
        for (int t = 0; t < 2; ++t)
#pragma unroll
        for (int bt = 0; bt < 4; ++bt) {
            xsq[t][bt] = 0.f;
#pragma unroll
            for (int kh = 0; kh < 2; ++kh) {
                const float* xp = in + (size_t)b * 262144
                                + (size_t)(kh * 32 + kg * 8) * 4096
                                + hw0 + t * 256 + wid * 64 + bt * 16 + l15;
                short8v v;
#pragma unroll
                for (int e = 0; e < 8; ++e) {
                    float x = xp[(size_t)e * 4096];
                    xsq[t][bt] = fmaf(x, x, xsq[t][bt]);
                    v[e] = bf16r(x);
                }
                xf[t][bt][kh] = v;
            }
        }

        asm volatile("s_waitcnt vmcnt(0) lgkmcnt(0)" ::: "memory");
        __builtin_amdgcn_sched_barrier(0);
        __builtin_amdgcn_s_barrier();                      // B1: staging done
        __builtin_amdgcn_sched_barrier(0);

        float lsum = 0.f;
#pragma unroll
        for (int t = 0; t < 2; ++t) {
            float rm[4];
#pragma unroll
            for (int bt = 0; bt < 4; ++bt) rm[bt] = -3.4e38f;

            for (int ct = 0; ct < 64; ++ct) {
                const int rbase = ct * 16 + l15;           // A-frag row = code
                const char* arow = (const char*)cbs + rbase * 128;
                const int sw = (rbase & 7) << 4;
                short8v a0 = *(const short8v*)(arow + (kgb ^ sw));
                short8v a1 = *(const short8v*)(arow + ((64 + kgb) ^ sw));
                f32x4 bsq4 = *(const f32x4*)&bsqs[ct * 16 + kg4];
                const unsigned jb = (unsigned)(ct * 16 + kg4);
#pragma unroll
                for (int bt = 0; bt < 4; ++bt) {
                    f32x4 acc = bsq4;
                    acc = __builtin_amdgcn_mfma_f32_16x16x32_bf16(a0, xf[t][bt][0], acc, 0, 0, 0);
                    acc = __builtin_amdgcn_mfma_f32_16x16x32_bf16(a1, xf[t][bt][1], acc, 0, 0, 0);
#pragma unroll
                    for (int r = 0; r < 4; ++r) {
                        unsigned pj = (__float_as_uint(acc[r]) & 0xFFFFFC00u) | (jb + r);
                        rm[bt] = fmaxf(rm[bt], __uint_as_float(pj));
                    }
                }
            }
            // cross-lane reduce: max over kg; idx + hist + loss
#pragma unroll
            for (int bt = 0; bt < 4; ++bt) {
                float m  = rm[bt];
                float xs = xsq[t][bt];
                m  = fmaxf(m, __shfl_xor(m, 16));
                xs += __shfl_xor(xs, 16);
                m  = fmaxf(m, __shfl_xor(m, 32));
                xs += __shfl_xor(xs, 32);
                if (kg == 0) {
                    unsigned mu = __float_as_uint(m);
                    int j = (int)(mu & 1023u);
                    float mval = __uint_as_float(mu & 0xFFFFFC00u);
                    idx_lds[t * 256 + wid * 64 + bt * 16 + l15] = j;
                    atomicAdd(&hist[j], 1u);
                    lsum += xs - 2.f * mval;   // |x-c|^2 = |x|^2 - 2(x.c - .5|c|^2)
                }
            }
            asm volatile("s_waitcnt lgkmcnt(0)" ::: "memory");
            __builtin_amdgcn_sched_barrier(0);
            __builtin_amdgcn_s_barrier();                  // B2 / B3: idx ready
            __builtin_amdgcn_sched_barrier(0);
        }

        // ---- q writes (fp32 gather; writers are streaming meanwhile) ----
#pragma unroll
        for (int t = 0; t < 2; ++t) {
            const int jf = idx_lds[t * 256 + tid];
            const float* cr = cb + (size_t)jf * HIDDEN;
            float* qp = out + OUT_Q_OFF + (size_t)b * 262144 + hw0 + t * 256 + tid;
#pragma unroll
            for (int c = 0; c < HIDDEN; ++c)
                qp[(size_t)c * 4096] = cr[c];    // quantized_st == q exactly
        }
        for (int k = tid; k < VOCAB; k += 256) {
            unsigned h = hist[k];
            if (h) atomicAdd(&counts[k], h);
        }
#pragma unroll
        for (int off = 32; off; off >>= 1) lsum += __shfl_down(lsum, off);
        if (lane == 0) atomicAdd(ws_loss, lsum);
    } else {
        // ======================= writer waves =======================
        const int w = tid - 256;                 // 0..127
        asm volatile("s_waitcnt vmcnt(0) lgkmcnt(0)" ::: "memory");
        __builtin_amdgcn_sched_barrier(0);
        __builtin_amdgcn_s_barrier();                      // B1
        __builtin_amdgcn_sched_barrier(0);

#pragma unroll
        for (int t = 0; t < 2; ++t) {
            __builtin_amdgcn_s_barrier();                  // B2 / B3: idx ready
            __builtin_amdgcn_sched_barrier(0);
            asm volatile("" ::: "memory");
            // stream this tile's one_hot floats with the 1.0 folded in.
            // float4 slot s covers flat floats [4s+2, 4s+6); tile0: s<65535,
            // tile1: 65535<=s<131071 (slot 65535 straddles rows 255/256).
            const int s0 = t ? 65535 : 0;
            const int s1 = t ? 131071 : 65535;
            for (int s = s0 + w; s < s1; s += 128) {
                const int f0 = 4 * s + 2;
                const int r  = f0 >> 10;
                const int j0 = f0 & 1023;
                const int ja = idx_lds[r];
                const int rb = (j0 == 1022) ? r + 1 : r;
                const int jb2 = idx_lds[rb];
                float4 v;
                v.x = (ja  == j0)              ? 1.f : 0.f;
                v.y = (ja  == j0 + 1)          ? 1.f : 0.f;
                v.z = (jb2 == ((j0 + 2) & 1023)) ? 1.f : 0.f;
                v.w = (jb2 == ((j0 + 3) & 1023)) ? 1.f : 0.f;
                oh4[s] = v;
            }
            if (t == 0 && w == 0) {            // head floats: row 0, j 0..1
                const int ja = idx_lds[0];
                *(float2*)ohflat = make_float2(ja == 0 ? 1.f : 0.f,
                                               ja == 1 ? 1.f : 0.f);
            }
            if (t == 1 && w == 127) {          // tail floats: row 511, j 1022..1023
                const int ja = idx_lds[511];
                *(float2*)(ohflat + 524286) = make_float2(ja == 1022 ? 1.f : 0.f,
                                                          ja == 1023 ? 1.f : 0.f);
            }
        }
    }
}

__global__ void vq_finalize(const unsigned* __restrict__ counts,
                            const float* __restrict__ ws_loss,
                            float* __restrict__ out)
{
    __shared__ double red[4];
    const int tid = threadIdx.x;
    double s = 0.0;
    for (int k = tid; k < VOCAB; k += 256) {
        double p = (double)counts[k] / (double)N_POS;
        s += -p * log(p + 1e-10);
    }
#pragma unroll
    for (int off = 32; off; off >>= 1) s += __shfl_down(s, off);
    if ((tid & 63) == 0) red[tid >> 6] = s;
    __syncthreads();
    if (tid == 0) {
        double e = red[0] + red[1] + red[2] + red[3];
        out[OUT_PPL_OFF] = (float)exp(e);
        out[0] = ws_loss[0] * 1.25f / (float)Q_ELEMS;
    }
}

extern "C" void kernel_launch(void* const* d_in, const int* in_sizes, int n_in,
                              void* d_out, int out_size, void* d_ws, size_t ws_size,
                              hipStream_t stream) {
    const float* in = (const float*)d_in[0];
    const float* cb = (const float*)d_in[1];
    float* out = (float*)d_out;

    float*    ws_loss = (float*)d_ws;                 // 4 B
    unsigned* counts  = (unsigned*)d_ws + 64;         // bytes 256..4352

    hipMemsetAsync(d_ws, 0, 4352, stream);            // zero loss accum + counts
    vq_main<<<NBLK, 384, 0, stream>>>(in, cb, out, ws_loss, counts);
    vq_finalize<<<1, 256, 0, stream>>>(counts, ws_loss, out);
}